// Round 7
// baseline (458.404 us; speedup 1.0000x reference)
//
#include <hip/hip_runtime.h>
#include <math.h>

// Problem constants
constexpr int BN  = 16;    // batch
constexpr int HH  = 224;
constexpr int WW  = 224;
constexpr int CI  = 8;     // input channels
constexpr int FF  = 256;   // filter feature dim
constexpr int NC  = 16;    // output channels
constexpr int NP  = 1152;  // CI*NC*3*3 dynamic params per sample
// patch index p = cin*9 + dy*3 + dx  (p < 72), w[b][p][c] = dyn[b][p*16+c]

__device__ __forceinline__ float elu_f(float x) {
    return x > 0.0f ? x : (__expf(x) - 1.0f);
}

// ---------------- kernel 1: h = elu(filter_inpt @ W1 + b1) -------------------
// grid 32 blocks (16 samples x 2 halves), 128 threads
__global__ __launch_bounds__(128) void k_h(const float* __restrict__ fi,
                                           const float* __restrict__ W1,
                                           const float* __restrict__ b1,
                                           float* __restrict__ h_out) {
    __shared__ float x[FF];
    int bid = blockIdx.x;
    int b = bid >> 1, half = bid & 1;
    int t = threadIdx.x;
    x[t]       = fi[b * FF + t];
    x[t + 128] = fi[b * FF + t + 128];
    __syncthreads();
    int col = half * 128 + t;
    float acc = b1[col];
#pragma unroll 8
    for (int k = 0; k < FF; ++k) acc = fmaf(x[k], W1[k * FF + col], acc);
    h_out[b * FF + col] = elu_f(acc);
}

// ------------- kernel 2: dyn = h@Wd + bd ; bias = h@Wb + bb + dfn ------------
// grid 160 blocks (16 samples x 10 jobs), 128 threads
__global__ __launch_bounds__(128) void k_dyn(const float* __restrict__ h_in,
                                             const float* __restrict__ Wd,
                                             const float* __restrict__ bd,
                                             const float* __restrict__ Wb,
                                             const float* __restrict__ bb,
                                             const float* __restrict__ dfn,
                                             float* __restrict__ w_out,
                                             float* __restrict__ bias_out) {
    __shared__ float hl[FF];
    int bid = blockIdx.x;
    int b = bid / 10, j = bid % 10;
    int t = threadIdx.x;
    hl[t]       = h_in[b * FF + t];
    hl[t + 128] = h_in[b * FF + t + 128];
    __syncthreads();
    if (j < 9) {
        int i = j * 128 + t;          // i < 1152
        float acc = bd[i];
#pragma unroll 8
        for (int k = 0; k < FF; ++k) acc = fmaf(hl[k], Wd[k * NP + i], acc);
        w_out[b * NP + i] = acc;
    } else if (t < NC) {
        float acc = bb[t] + dfn[t];
        for (int k = 0; k < FF; ++k) acc = fmaf(hl[k], Wb[k * NC + t], acc);
        bias_out[b * NC + t] = acc;
    }
}

// ---------------- kernel 3: dynamic 3x3 conv + bias + elu --------------------
// LANE = (channel, pixel-group) layout: c = lane&15, pg = lane>>4.
// Each lane computes 8 consecutive x-pixels of ONE output channel -> acc[8].
// Weights are per-lane VECTOR loads (24 dwords per dy, lanes c=0..15 read 64
// contiguous bytes; 4.6 KB/sample stays L2-hot). Input reads are 16-way
// same-address broadcast, HW-coalesced. No LDS, no __syncthreads, no
// wave-uniform weight fetch -> none of the measured sink/spill pathologies.
// Per-thread working set ~60 VGPR; launch_bounds(256,6) caps at ~85.
// Block = 4 waves = 4 consecutive rows x 32 px of one sample.
__global__ __launch_bounds__(256, 6) void k_conv(const float* __restrict__ in,
                                                 const float* __restrict__ w_all,
                                                 const float* __restrict__ bias_all,
                                                 float* __restrict__ out) {
    const int b    = blockIdx.z;
    const int t    = threadIdx.x;
    const int wid  = t >> 6;                 // wave -> row offset 0..3
    const int lane = t & 63;
    const int c    = lane & 15;              // output channel
    const int pg   = lane >> 4;              // pixel group 0..3 (8 px each)
    const int y    = blockIdx.y * 4 + wid;
    const int xb   = blockIdx.x * 32 + pg * 8;   // first output px of this lane

    const float* __restrict__ wqc = w_all + b * NP + c;   // index by p*NC

    float acc[8];
    {
        const float bias = bias_all[b * NC + c];
#pragma unroll
        for (int j = 0; j < 8; ++j) acc[j] = bias;
    }

    const bool interior = (blockIdx.x != 0) && (blockIdx.x != 6) &&
                          (blockIdx.y != 0) && (blockIdx.y != 55);

    if (interior) {
#pragma unroll 1
        for (int dy = 0; dy < 3; ++dy) {
            // this dy's 24 weights for channel c (per-lane vector loads)
            float wr[24];
#pragma unroll
            for (int cin = 0; cin < 8; ++cin)
#pragma unroll
                for (int dx = 0; dx < 3; ++dx)
                    wr[cin * 3 + dx] = wqc[(cin * 9 + dy * 3 + dx) * NC];

            const float* __restrict__ rp =
                in + ((size_t)(b * HH + y + dy - 1) * WW + (xb - 1)) * CI;
#pragma unroll
            for (int i = 0; i < 10; ++i) {      // input px xb-1+i
                const float4 a0 = ((const float4*)(rp + i * CI))[0];
                const float4 a1 = ((const float4*)(rp + i * CI))[1];
                const float v8[8] = {a0.x, a0.y, a0.z, a0.w,
                                     a1.x, a1.y, a1.z, a1.w};
#pragma unroll
                for (int cin = 0; cin < 8; ++cin) {
                    const float v = v8[cin];
#pragma unroll
                    for (int dx = 0; dx < 3; ++dx) {
                        const int j = i - dx;   // output px slot
                        if (j >= 0 && j < 8)
                            acc[j] = fmaf(v, wr[cin * 3 + dx], acc[j]);
                    }
                }
            }
        }
    } else {
#pragma unroll 1
        for (int dy = 0; dy < 3; ++dy) {
            float wr[24];
#pragma unroll
            for (int cin = 0; cin < 8; ++cin)
#pragma unroll
                for (int dx = 0; dx < 3; ++dx)
                    wr[cin * 3 + dx] = wqc[(cin * 9 + dy * 3 + dx) * NC];

            const int  vy  = y + dy - 1;
            const bool oky = (unsigned)vy < (unsigned)HH;
            const int  cy  = min(max(vy, 0), HH - 1);
            const float* __restrict__ rowp =
                in + ((size_t)(b * HH + cy) * WW) * CI;
#pragma unroll
            for (int i = 0; i < 10; ++i) {
                const int  col = xb - 1 + i;
                const bool ok  = oky && ((unsigned)col < (unsigned)WW);
                const int  cc  = min(max(col, 0), WW - 1);
                const float4 a0 = ((const float4*)(rowp + (size_t)cc * CI))[0];
                const float4 a1 = ((const float4*)(rowp + (size_t)cc * CI))[1];
                float v8[8] = {a0.x, a0.y, a0.z, a0.w,
                               a1.x, a1.y, a1.z, a1.w};
#pragma unroll
                for (int k = 0; k < 8; ++k) v8[k] = ok ? v8[k] : 0.0f;
#pragma unroll
                for (int cin = 0; cin < 8; ++cin) {
                    const float v = v8[cin];
#pragma unroll
                    for (int dx = 0; dx < 3; ++dx) {
                        const int j = i - dx;
                        if (j >= 0 && j < 8)
                            acc[j] = fmaf(v, wr[cin * 3 + dx], acc[j]);
                    }
                }
            }
        }
    }

    // ---- epilogue: elu + store 8 px of this lane's channel ----
    float* __restrict__ op = out + ((size_t)(b * HH + y) * WW + xb) * NC + c;
#pragma unroll
    for (int j = 0; j < 8; ++j) op[j * NC] = elu_f(acc[j]);
}

extern "C" void kernel_launch(void* const* d_in, const int* in_sizes, int n_in,
                              void* d_out, int out_size, void* d_ws, size_t ws_size,
                              hipStream_t stream) {
    const float* inpt = (const float*)d_in[0];
    const float* fi   = (const float*)d_in[1];
    const float* W1   = (const float*)d_in[2];
    const float* b1   = (const float*)d_in[3];
    const float* Wd   = (const float*)d_in[4];
    const float* bd   = (const float*)d_in[5];
    const float* Wb   = (const float*)d_in[6];
    const float* bb   = (const float*)d_in[7];
    const float* dfn  = (const float*)d_in[8];
    float* out = (float*)d_out;

    float* ws    = (float*)d_ws;
    float* h     = ws;                    // 16*256   = 4096 floats
    float* wDyn  = ws + 4096;             // 16*1152  = 18432 floats
    float* biasA = ws + 4096 + 18432;     // 16*16    = 256 floats

    k_h  <<<32, 128, 0, stream>>>(fi, W1, b1, h);
    k_dyn<<<160, 128, 0, stream>>>(h, Wd, bd, Wb, bb, dfn, wDyn, biasA);
    k_conv<<<dim3(7, 56, BN), 256, 0, stream>>>(inpt, wDyn, biasA, out);
}

// Round 8
// 50.395 us; speedup vs baseline: 9.0963x; 9.0963x over previous
//
#include <hip/hip_runtime.h>
#include <math.h>

// Problem constants
constexpr int BN  = 16;    // batch
constexpr int HH  = 224;
constexpr int WW  = 224;
constexpr int CI  = 8;     // input channels
constexpr int FF  = 256;   // filter feature dim
constexpr int NC  = 16;    // output channels
constexpr int NP  = 1152;  // CI*NC*3*3 dynamic params per sample
// reference patch index p = cin*9 + dy*3 + dx ; w[b][p][c] = dyn[b][p*16+c]
// MFMA K-ordering used here: k = tap*8 + cin, tap = dy*3+dx (taps 9..11 pad=0)

typedef __attribute__((ext_vector_type(8))) short short8;   // 8 bf16 = 4 VGPR
typedef __attribute__((ext_vector_type(4))) float f32x4;

__device__ __forceinline__ float elu_f(float x) {
    return x > 0.0f ? x : (__expf(x) - 1.0f);
}

// split f32 -> bf16 hi (truncate) + bf16 lo (residual, truncate): v ~= hi+lo
__device__ __forceinline__ void split8(const float* v, short8& hi, short8& lo) {
#pragma unroll
    for (int j = 0; j < 8; ++j) {
        const unsigned u = __float_as_uint(v[j]);
        hi[j] = (short)(u >> 16);
        const float hf = __uint_as_float(u & 0xffff0000u);
        lo[j] = (short)(__float_as_uint(v[j] - hf) >> 16);
    }
}

// ---------------- kernel 1: h = elu(filter_inpt @ W1 + b1) -------------------
__global__ __launch_bounds__(128) void k_h(const float* __restrict__ fi,
                                           const float* __restrict__ W1,
                                           const float* __restrict__ b1,
                                           float* __restrict__ h_out) {
    __shared__ float x[FF];
    int bid = blockIdx.x;
    int b = bid >> 1, half = bid & 1;
    int t = threadIdx.x;
    x[t]       = fi[b * FF + t];
    x[t + 128] = fi[b * FF + t + 128];
    __syncthreads();
    int col = half * 128 + t;
    float acc = b1[col];
#pragma unroll 8
    for (int k = 0; k < FF; ++k) acc = fmaf(x[k], W1[k * FF + col], acc);
    h_out[b * FF + col] = elu_f(acc);
}

// ------------- kernel 2: dyn = h@Wd + bd ; bias = h@Wb + bb + dfn ------------
__global__ __launch_bounds__(128) void k_dyn(const float* __restrict__ h_in,
                                             const float* __restrict__ Wd,
                                             const float* __restrict__ bd,
                                             const float* __restrict__ Wb,
                                             const float* __restrict__ bb,
                                             const float* __restrict__ dfn,
                                             float* __restrict__ w_out,
                                             float* __restrict__ bias_out) {
    __shared__ float hl[FF];
    int bid = blockIdx.x;
    int b = bid / 10, j = bid % 10;
    int t = threadIdx.x;
    hl[t]       = h_in[b * FF + t];
    hl[t + 128] = h_in[b * FF + t + 128];
    __syncthreads();
    if (j < 9) {
        int i = j * 128 + t;          // i < 1152
        float acc = bd[i];
#pragma unroll 8
        for (int k = 0; k < FF; ++k) acc = fmaf(hl[k], Wd[k * NP + i], acc);
        w_out[b * NP + i] = acc;
    } else if (t < NC) {
        float acc = bb[t] + dfn[t];
        for (int k = 0; k < FF; ++k) acc = fmaf(hl[k], Wb[k * NC + t], acc);
        bias_out[b * NC + t] = acc;
    }
}

// ---------------- kernel 3: dynamic conv as per-sample MFMA GEMM -------------
// C[px,c] = patches[px, k] * B[k, c], K = 96 (12 taps x 8 cin, taps 9-11 pad).
// mfma_f32_16x16x32_bf16 layouts (lane l):
//   A: row = l&15 (pixel), k = (l>>4)*8 + i  -> one 32B NHWC load per chunk
//   B: col = l&15 (channel), k = (l>>4)*8+i  -> loaded once per wave (24 regs)
//   C: col = l&15 (channel), row = (l>>4)*4 + r (pixel)
// Precision: bf16 hi/lo split, acc += hi*hi + lo*hi + hi*lo (two acc chains).
// Block = 128 thr = 2 waves = 2 rows; each wave does 14 x 16-px tiles of row y.
__global__ __launch_bounds__(128) void k_conv(const float* __restrict__ in,
                                              const float* __restrict__ w_all,
                                              const float* __restrict__ bias_all,
                                              float* __restrict__ out) {
    const int b    = blockIdx.y;
    const int t    = threadIdx.x;
    const int wid  = t >> 6;
    const int lane = t & 63;
    const int cl   = lane & 15;        // A-row pixel idx / B,C channel idx
    const int g    = lane >> 4;        // k-group 0..3
    const int y    = blockIdx.x * 2 + wid;

    // ---- per-lane tap geometry for the 3 k-chunks ----
    int  dyL[3], dxL[3];
    bool real[3];
#pragma unroll
    for (int c = 0; c < 3; ++c) {
        const int tap = c * 4 + g;
        real[c] = (tap < 9);
        const int tp = real[c] ? tap : 0;
        dyL[c] = tp / 3;
        dxL[c] = tp - 3 * dyL[c];
    }

    // ---- B fragments (hi/lo), loaded once per wave ----
    const float* __restrict__ wq = w_all + b * NP;
    short8 bhi0, blo0, bhi1, blo1, bhi2, blo2;
    {
        float wv[8];
#pragma unroll
        for (int i = 0; i < 8; ++i)
            wv[i] = real[0] ? wq[(i * 9 + (0 * 4 + g)) * NC + cl] : 0.0f;
        split8(wv, bhi0, blo0);
#pragma unroll
        for (int i = 0; i < 8; ++i)
            wv[i] = real[1] ? wq[(i * 9 + (1 * 4 + g)) * NC + cl] : 0.0f;
        split8(wv, bhi1, blo1);
#pragma unroll
        for (int i = 0; i < 8; ++i)
            wv[i] = real[2] ? wq[(i * 9 + (2 * 4 + g)) * NC + cl] : 0.0f;
        split8(wv, bhi2, blo2);
    }

    // ---- per-chunk input row base + validity ----
    size_t ro[3];
    bool   okr[3];
#pragma unroll
    for (int c = 0; c < 3; ++c) {
        const int iy = y + dyL[c] - 1;
        okr[c] = real[c] && ((unsigned)iy < (unsigned)HH);
        const int iyc = min(max(iy, 0), HH - 1);
        ro[c] = ((size_t)(b * HH + iyc) * WW) * CI;
    }

    const float bias = bias_all[b * NC + cl];
    const size_t orow = ((size_t)(b * HH + y) * WW) * NC;

#pragma unroll 1
    for (int tx = 0; tx < 14; ++tx) {
        const int x0 = tx * 16;
        f32x4 accM = {bias, bias, bias, bias};   // hi*hi
        f32x4 accC = {0.f, 0.f, 0.f, 0.f};       // corrections

#pragma unroll
        for (int c = 0; c < 3; ++c) {
            const int  ix = x0 + cl + dxL[c] - 1;
            const bool ok = okr[c] && ((unsigned)ix < (unsigned)WW);
            const int  ixc = min(max(ix, 0), WW - 1);
            const float4* pp = (const float4*)(in + ro[c] + (size_t)ixc * CI);
            const float4 a0 = pp[0];
            const float4 a1 = pp[1];
            float av[8];
            av[0] = ok ? a0.x : 0.0f;
            av[1] = ok ? a0.y : 0.0f;
            av[2] = ok ? a0.z : 0.0f;
            av[3] = ok ? a0.w : 0.0f;
            av[4] = ok ? a1.x : 0.0f;
            av[5] = ok ? a1.y : 0.0f;
            av[6] = ok ? a1.z : 0.0f;
            av[7] = ok ? a1.w : 0.0f;
            short8 ahi, alo;
            split8(av, ahi, alo);
            const short8 bh = (c == 0) ? bhi0 : (c == 1) ? bhi1 : bhi2;
            const short8 bl = (c == 0) ? blo0 : (c == 1) ? blo1 : blo2;
            accM = __builtin_amdgcn_mfma_f32_16x16x32_bf16(ahi, bh, accM, 0, 0, 0);
            accC = __builtin_amdgcn_mfma_f32_16x16x32_bf16(alo, bh, accC, 0, 0, 0);
            accC = __builtin_amdgcn_mfma_f32_16x16x32_bf16(ahi, bl, accC, 0, 0, 0);
        }

        // ---- epilogue: elu + store (lane cl = channel, rows g*4+r = pixel) --
#pragma unroll
        for (int r = 0; r < 4; ++r) {
            const int px = g * 4 + r;
            out[orow + (size_t)(x0 + px) * NC + cl] = elu_f(accM[r] + accC[r]);
        }
    }
}

extern "C" void kernel_launch(void* const* d_in, const int* in_sizes, int n_in,
                              void* d_out, int out_size, void* d_ws, size_t ws_size,
                              hipStream_t stream) {
    const float* inpt = (const float*)d_in[0];
    const float* fi   = (const float*)d_in[1];
    const float* W1   = (const float*)d_in[2];
    const float* b1   = (const float*)d_in[3];
    const float* Wd   = (const float*)d_in[4];
    const float* bd   = (const float*)d_in[5];
    const float* Wb   = (const float*)d_in[6];
    const float* bb   = (const float*)d_in[7];
    const float* dfn  = (const float*)d_in[8];
    float* out = (float*)d_out;

    float* ws    = (float*)d_ws;
    float* h     = ws;                    // 16*256   = 4096 floats
    float* wDyn  = ws + 4096;             // 16*1152  = 18432 floats
    float* biasA = ws + 4096 + 18432;     // 16*16    = 256 floats

    k_h  <<<32, 128, 0, stream>>>(fi, W1, b1, h);
    k_dyn<<<160, 128, 0, stream>>>(h, Wd, bd, Wb, bb, dfn, wDyn, biasA);
    k_conv<<<dim3(112, BN), 128, 0, stream>>>(inpt, wDyn, biasA, out);
}